// Round 6
// baseline (180.159 us; speedup 1.0000x reference)
//
#include <hip/hip_runtime.h>

typedef __attribute__((ext_vector_type(8))) short bf16x8;
typedef __attribute__((ext_vector_type(4))) float f32x4;
typedef __attribute__((ext_vector_type(8))) unsigned short u16x8;

#define DEVINL __device__ __forceinline__

constexpr int NI = 256;   // input channels (K)
constexpr int NO = 256;   // output channels
constexpr int NC = 120;   // irrep feature width
constexpr int WELEMS = 56 * NO * NI;                 // 3,670,016
constexpr size_t XT_ELEMS = (size_t)NC * 1024 * NI;  // 31,457,280

DEVINL ushort f2bf(float x) {   // round-to-nearest-even fp32 -> bf16 bits
  unsigned u = __float_as_uint(x);
  u += 0x7FFFu + ((u >> 16) & 1u);
  return (ushort)(u >> 16);
}

constexpr int mat_of(int c) {   // column c -> weight-matrix id (0..55); monotone
  return c < 32 ? c : (c < 80 ? 32 + (c - 32) / 3 : 48 + (c - 80) / 5);
}

// ---- prep: wb[((m*32 + k/8)*256 + o)*8 + k%8] = bf16(W_m[o][k]) ----
__global__ __launch_bounds__(256) void prep_w(const float* __restrict__ w0,
                                              const float* __restrict__ w1,
                                              const float* __restrict__ w2,
                                              ushort* __restrict__ wb) {
  const int m = blockIdx.x >> 5;        // 0..55
  const int kc = blockIdx.x & 31;       // k-chunk of 8
  const int o = threadIdx.x;            // 0..255
  const float* src;
  if (m < 32)      src = w0 + ((size_t)(m * NO + o)) * NI;
  else if (m < 48) src = w1 + ((size_t)((m - 32) * NO + o)) * NI;
  else             src = w2 + ((size_t)((m - 48) * NO + o)) * NI;
  src += kc * 8;
  float4 a = *reinterpret_cast<const float4*>(src);
  float4 b = *reinterpret_cast<const float4*>(src + 4);
  u16x8 p = { f2bf(a.x), f2bf(a.y), f2bf(a.z), f2bf(a.w),
              f2bf(b.x), f2bf(b.y), f2bf(b.z), f2bf(b.w) };
  *reinterpret_cast<u16x8*>(wb + ((size_t)(blockIdx.x * 256 + o)) * 8) = p;
}

// ---- pass 1: x [1024][256 i][120 c] f32 -> xT [120 c][1024 b][256 i] bf16 ----
__global__ __launch_bounds__(256) void xpose(const float* __restrict__ x,
                                             ushort* __restrict__ xt) {
  __shared__ ushort tl[120 * 256];     // addr(c,i) = c*256 + (i ^ ((c&7)<<3)), 60 KB
  const int b = blockIdx.x;            // 1024 blocks, one b each
  const int t = threadIdx.x;
  const float* xb = x + (size_t)b * (NI * NC);
#pragma unroll
  for (int j = 0; j < 30; ++j) {       // 30*1024 = 30720 elems, f32x4 coalesced
    const int e = j * 1024 + t * 4;    // c = e%120 is a multiple of 4 -> no row wrap
    f32x4 v = *reinterpret_cast<const f32x4*>(xb + e);
    const int i = e / 120, c = e % 120;
#pragma unroll
    for (int k = 0; k < 4; ++k)
      tl[(c + k) * 256 + (i ^ (((c + k) & 7) << 3))] = f2bf(v[k]);
  }
  __syncthreads();
  ushort* dst = xt + (size_t)b * 256;
#pragma unroll
  for (int q = 0; q < 15; ++q) {       // 3840 chunks of 8 i, 15 per thread
    const int chunk = q * 256 + t;
    const int c = chunk >> 5, i0 = (chunk & 31) * 8;
    u16x8 v = *reinterpret_cast<const u16x8*>(&tl[c * 256 + (i0 ^ ((c & 7) << 3))]);
    *reinterpret_cast<u16x8*>(dst + (size_t)c * (1024 * NI) + i0) = v;
  }
}

// ---- pass 2: templated per c-tile, XCD-pinned, burst W preload ----
// block = [8 c] x [16 b] x [256 o], 8 waves; K in 4 stages of 64 via LDS.
template<int CT>
DEVINL void body(const ushort* __restrict__ xt, const ushort* __restrict__ wb,
                 const float* __restrict__ bias0, float* __restrict__ out,
                 int bt, ushort* xs) {
  constexpr int c0 = CT * 8;
  constexpr int M0 = mat_of(c0);
  constexpr int NM = mat_of(c0 + 7) - M0 + 1;   // 2..8 distinct matrices in tile
  constexpr int NF = NM * 2;                    // fragments per k-half burst (<=16)

  const int t = threadIdx.x, lane = t & 63, wid = t >> 6;
  const int bg = bt * 16;
  const int sb = lane >> 2, sp = lane & 3;      // staging: c=wid, b=sb, k-part=sp
  const int rb = lane & 15, rg = lane >> 4;     // frag row (b), k-group
  const int oc = wid * 16 + rb;                 // o-col (+ of*128)

  const int srow = (wid * 16 + sb) * 64;        // LDS row; elem k at k ^ ((b&7)<<3)
  const int sk0 = (sp * 16) ^ ((sb & 7) << 3);
  const int sk1 = (sp * 16 + 8) ^ ((sb & 7) << 3);
  const ushort* xsrc = xt + (size_t)(c0 + wid) * (1024 * NI)
                          + (size_t)(bg + sb) * NI + sp * 16;

  f32x4 acc[8][2];
#pragma unroll
  for (int i = 0; i < 8; ++i) { acc[i][0] = (f32x4)0.0f; acc[i][1] = (f32x4)0.0f; }

  u16x8 v0 = *reinterpret_cast<const u16x8*>(xsrc);      // preload stage 0
  u16x8 v1 = *reinterpret_cast<const u16x8*>(xsrc + 8);

#pragma unroll 1
  for (int s = 0; s < 4; ++s) {
    if (s) __syncthreads();            // compute(s-1) done before overwrite
    *reinterpret_cast<u16x8*>(&xs[srow + sk0]) = v0;
    *reinterpret_cast<u16x8*>(&xs[srow + sk1]) = v1;
    __syncthreads();
    if (s < 3) {                       // prefetch next stage during compute
      v0 = *reinterpret_cast<const u16x8*>(xsrc + (s + 1) * 64);
      v1 = *reinterpret_cast<const u16x8*>(xsrc + (s + 1) * 64 + 8);
    }

#pragma unroll
    for (int p = 0; p < 2; ++p) {      // two k-halves per stage
      // burst-issue ALL W fragments for this k-half: independent loads,
      // consumed below with compiler-counted vmcnt (one latency, not NM serial)
      bf16x8 wf[NF];                   // static indices only (full unroll)
#pragma unroll
      for (int j = 0; j < NF; ++j) {
        const int m = M0 + (j >> 1);
        const ushort* wp = wb + ((size_t)((m * 32 + s * 8 + p * 4 + rg) * NO
                                          + oc + (j & 1) * 128)) * 8;
        wf[j] = *reinterpret_cast<const bf16x8*>(wp);
      }
#pragma unroll
      for (int cc = 0; cc < 8; ++cc) {
        const int dm = mat_of(c0 + cc) - M0;    // compile-time per template
        const ushort* xp = xs + (cc * 16 + rb) * 64;
        const int sz = (rb & 7) << 3;
        bf16x8 a = *reinterpret_cast<const bf16x8*>(xp + ((p * 32 + rg * 8) ^ sz));
        acc[cc][0] = __builtin_amdgcn_mfma_f32_16x16x32_bf16(a, wf[dm * 2 + 0], acc[cc][0], 0, 0, 0);
        acc[cc][1] = __builtin_amdgcn_mfma_f32_16x16x32_bf16(a, wf[dm * 2 + 1], acc[cc][1], 0, 0, 0);
      }
    }
  }

  if constexpr (CT < 4) {              // l=0 irreps (c<32): bias b0[m=c][o]
#pragma unroll
    for (int cc = 0; cc < 8; ++cc) {
      acc[cc][0] += bias0[(c0 + cc) * NO + oc];
      acc[cc][1] += bias0[(c0 + cc) * NO + oc + 128];
    }
  }

  const int br0 = bg + rg * 4;         // D row = (lane>>4)*4 + reg
#pragma unroll
  for (int of = 0; of < 2; ++of)
#pragma unroll
    for (int r = 0; r < 4; ++r) {
      float4 va = make_float4(acc[0][of][r], acc[1][of][r], acc[2][of][r], acc[3][of][r]);
      float4 vb = make_float4(acc[4][of][r], acc[5][of][r], acc[6][of][r], acc[7][of][r]);
      float* dst = out + ((size_t)(br0 + r) * NO + oc + of * 128) * NC + c0;
      *reinterpret_cast<float4*>(dst) = va;
      *reinterpret_cast<float4*>(dst + 4) = vb;
    }
}

__global__ __launch_bounds__(512, 2) void e3mix3(const ushort* __restrict__ xt,
                                                 const ushort* __restrict__ wb,
                                                 const float* __restrict__ bias0,
                                                 float* __restrict__ out) {
  __shared__ ushort xs[8 * 16 * 64];   // 16 KB
  const int bid = blockIdx.x;          // 1024 = 64 bt x 16 slots
  const int s4 = bid & 15;
  const int bt = bid >> 4;
  // XCD = bid % 8 = s4 % 8 (16 | bt<<4). XCD k serves ct in {2k, 2k+1}:
  // W slice <= 2 MB -> L2-resident per XCD; only 2 code variants per CU.
  const int ct = ((s4 & 7) << 1) | (s4 >> 3);
  if (ct == 15) return;                // 120 = 15 tiles of 8; slot 15 idle
  switch (ct) {
    case 0:  body<0 >(xt, wb, bias0, out, bt, xs); break;
    case 1:  body<1 >(xt, wb, bias0, out, bt, xs); break;
    case 2:  body<2 >(xt, wb, bias0, out, bt, xs); break;
    case 3:  body<3 >(xt, wb, bias0, out, bt, xs); break;
    case 4:  body<4 >(xt, wb, bias0, out, bt, xs); break;
    case 5:  body<5 >(xt, wb, bias0, out, bt, xs); break;
    case 6:  body<6 >(xt, wb, bias0, out, bt, xs); break;
    case 7:  body<7 >(xt, wb, bias0, out, bt, xs); break;
    case 8:  body<8 >(xt, wb, bias0, out, bt, xs); break;
    case 9:  body<9 >(xt, wb, bias0, out, bt, xs); break;
    case 10: body<10>(xt, wb, bias0, out, bt, xs); break;
    case 11: body<11>(xt, wb, bias0, out, bt, xs); break;
    case 12: body<12>(xt, wb, bias0, out, bt, xs); break;
    case 13: body<13>(xt, wb, bias0, out, bt, xs); break;
    default: body<14>(xt, wb, bias0, out, bt, xs); break;
  }
}

// ---- fallback (small ws): direct strided gather from x, validated in R5 ----
__global__ __launch_bounds__(512, 4) void e3mix2f(const float* __restrict__ x,
                                                  const ushort* __restrict__ wb,
                                                  const float* __restrict__ bias0,
                                                  float* __restrict__ out) {
  __shared__ ushort xs[8 * 16 * 64];
  const int bid = blockIdx.x;          // 960 = 15 ct * 64 bt
  const int ct = bid % 15, bt = bid / 15;
  const int c0 = ct * 8, bg = bt * 16;
  const int t = threadIdx.x, lane = t & 63, wid = t >> 6;
  const int sb = lane >> 2, sp = lane & 3;
  const int rb = lane & 15, rg = lane >> 4;
  const int oc = wid * 16 + rb;
  const int srow = (wid * 16 + sb) * 64;
  const int sk0 = (sp * 16) ^ ((sb & 7) << 3);
  const int sk1 = (sp * 16 + 8) ^ ((sb & 7) << 3);

  f32x4 acc[8][2];
#pragma unroll
  for (int i = 0; i < 8; ++i) { acc[i][0] = (f32x4)0.0f; acc[i][1] = (f32x4)0.0f; }
  bf16x8 w00 = {}, w01 = {}, w10 = {}, w11 = {};

#pragma unroll 1
  for (int s = 0; s < 4; ++s) {
    if (s) __syncthreads();
    u16x8 v0, v1;
    const float* src = x + (size_t)(bg + sb) * (NI * NC)
                         + (size_t)(s * 64 + sp * 16) * NC + (c0 + wid);
#pragma unroll
    for (int jj = 0; jj < 8; ++jj) v0[jj] = f2bf(src[jj * NC]);
#pragma unroll
    for (int jj = 0; jj < 8; ++jj) v1[jj] = f2bf(src[(8 + jj) * NC]);
    *reinterpret_cast<u16x8*>(&xs[srow + sk0]) = v0;
    *reinterpret_cast<u16x8*>(&xs[srow + sk1]) = v1;
    __syncthreads();

    int mprev = -1;
#pragma unroll
    for (int cc = 0; cc < 8; ++cc) {
      const int c = c0 + cc;
      const int m = c < 32 ? c : (c < 80 ? 32 + (c - 32) / 3 : 48 + (c - 80) / 5);
      if (m != mprev) {
        const ushort* wp = wb + ((size_t)((m * 32 + s * 8 + rg) * NO + oc)) * 8;
        w00 = *reinterpret_cast<const bf16x8*>(wp);
        w10 = *reinterpret_cast<const bf16x8*>(wp + (size_t)4 * NO * 8);
        w01 = *reinterpret_cast<const bf16x8*>(wp + 128 * 8);
        w11 = *reinterpret_cast<const bf16x8*>(wp + (size_t)4 * NO * 8 + 128 * 8);
        mprev = m;
      }
      const ushort* xp = xs + (cc * 16 + rb) * 64;
      const int sz = (rb & 7) << 3;
      bf16x8 a0 = *reinterpret_cast<const bf16x8*>(xp + ((rg * 8) ^ sz));
      bf16x8 a1 = *reinterpret_cast<const bf16x8*>(xp + ((32 + rg * 8) ^ sz));
      acc[cc][0] = __builtin_amdgcn_mfma_f32_16x16x32_bf16(a0, w00, acc[cc][0], 0, 0, 0);
      acc[cc][0] = __builtin_amdgcn_mfma_f32_16x16x32_bf16(a1, w10, acc[cc][0], 0, 0, 0);
      acc[cc][1] = __builtin_amdgcn_mfma_f32_16x16x32_bf16(a0, w01, acc[cc][1], 0, 0, 0);
      acc[cc][1] = __builtin_amdgcn_mfma_f32_16x16x32_bf16(a1, w11, acc[cc][1], 0, 0, 0);
    }
  }

  if (c0 < 32) {
#pragma unroll
    for (int cc = 0; cc < 8; ++cc) {
      acc[cc][0] += bias0[(c0 + cc) * NO + oc];
      acc[cc][1] += bias0[(c0 + cc) * NO + oc + 128];
    }
  }

  const int br0 = bg + rg * 4;
#pragma unroll
  for (int of = 0; of < 2; ++of)
#pragma unroll
    for (int r = 0; r < 4; ++r) {
      float4 va = make_float4(acc[0][of][r], acc[1][of][r], acc[2][of][r], acc[3][of][r]);
      float4 vb = make_float4(acc[4][of][r], acc[5][of][r], acc[6][of][r], acc[7][of][r]);
      float* dst = out + ((size_t)(br0 + r) * NO + oc + of * 128) * NC + c0;
      *reinterpret_cast<float4*>(dst) = va;
      *reinterpret_cast<float4*>(dst + 4) = vb;
    }
}

extern "C" void kernel_launch(void* const* d_in, const int* in_sizes, int n_in,
                              void* d_out, int out_size, void* d_ws, size_t ws_size,
                              hipStream_t stream) {
  const float* x  = (const float*)d_in[0];
  const float* w0 = (const float*)d_in[1];
  const float* w1 = (const float*)d_in[2];
  const float* w2 = (const float*)d_in[3];
  const float* b0 = (const float*)d_in[4];
  float* out = (float*)d_out;
  ushort* wb = (ushort*)d_ws;                       // 7.34 MB
  ushort* xt = wb + WELEMS;                         // +62.9 MB

  prep_w<<<56 * 32, 256, 0, stream>>>(w0, w1, w2, wb);
  const bool big = ws_size >= (size_t)2 * (WELEMS + XT_ELEMS);
  if (big) {
    xpose<<<1024, 256, 0, stream>>>(x, xt);
    e3mix3<<<1024, 512, 0, stream>>>(xt, wb, b0, out);
  } else {
    e3mix2f<<<960, 512, 0, stream>>>(x, wb, b0, out);
  }
}